// Round 4
// baseline (209.222 us; speedup 1.0000x reference)
//
#include <hip/hip_runtime.h>

// YOLO loss: preds (B,7,7,30) f32, labels (B,7,7,30) f32 -> scalar f32 (sum/B).
// R5 (fourth submit; rounds 1-3 all hit "container failed twice" acquisition
// errors — kernel never executed). Drop LDS staging entirely. R4's counters
// showed a latency-bound convoy (Occupancy 15% from 60.5KB LDS cap = 2
// blocks/CU; all waves drain vmcnt(0) at the barrier then compute with memory
// idle; VALUBusy 10%, HBM 17%). Per-thread data is 30 contiguous floats
// (8B-aligned) -> 15x float2 direct loads, coalesced at line granularity. The
// transposed labels[b,x,y,0] quirk is a single 4B gather that hits L1/L2
// (line fetched by neighbor threads). No barrier, no LDS cap -> 4x occupancy,
// loads overlap compute per-wave.

#define BATCH 16384
#define S 7
#define C 30
#define NCELLS (BATCH * S * S)   // 802816
#define BLOCK 256
#define NBLK (NCELLS / BLOCK)    // 3136, one cell per thread

__device__ __forceinline__ float sq(float v) { return v * v; }

__device__ __forceinline__ float2 ld2(const float* a) {
    return *reinterpret_cast<const float2*>(a);
}

__device__ __forceinline__ float iou_box(float acx, float acy, float aw, float ah,
                                         float bcx, float bcy, float bw, float bh) {
    float ax0 = acx - aw * 0.5f, ax1 = acx + aw * 0.5f;
    float ay0 = acy - ah * 0.5f, ay1 = acy + ah * 0.5f;
    float bx0 = bcx - bw * 0.5f, bx1 = bcx + bw * 0.5f;
    float by0 = bcy - bh * 0.5f, by1 = bcy + bh * 0.5f;
    float iw = fmaxf(fminf(ax1, bx1) - fmaxf(ax0, bx0), 0.0f);
    float ih = fmaxf(fminf(ay1, by1) - fmaxf(ay0, by0), 0.0f);
    float inter = iw * ih;
    float denom = aw * ah + bw * bh - inter + 1e-10f;
    return inter / denom;
}

__global__ __launch_bounds__(BLOCK, 4) void yolo_partial_kernel(
        const float* __restrict__ preds,
        const float* __restrict__ labels,
        float* __restrict__ partials) {
    const int tid  = threadIdx.x;
    const int cell = blockIdx.x * BLOCK + tid;

    const float* p = preds  + (size_t)cell * C;
    const float* l = labels + (size_t)cell * C;

    // transposed label x-coord quirk: labels[b, x, y, 0] (4B gather, L1/L2 hit)
    const int b   = cell / (S * S);
    const int rem = cell - b * (S * S);
    const int y   = rem / S;
    const int x   = rem - y * S;
    const int pc  = b * (S * S) + x * S + y;
    const float lb0 = labels[(size_t)pc * C];

    // box channels 0..9 (cell base is 120B -> 8B aligned, float2 legal)
    float2 p01 = ld2(p + 0), p23 = ld2(p + 2), p45 = ld2(p + 4),
           p67 = ld2(p + 6), p89 = ld2(p + 8);
    float2 l01 = ld2(l + 0), l23 = ld2(l + 2), l45 = ld2(l + 4),
           l67 = ld2(l + 6), l89 = ld2(l + 8);

    // class channels 10..29, streamed (no need to keep live)
    float cls = 0.0f;
    #pragma unroll
    for (int c = 10; c < C; c += 2) {
        float2 tp = ld2(p + c);
        float2 tl = ld2(l + c);
        cls += sq(tl.x - tp.x) + sq(tl.y - tp.y);
    }

    // lbox = (lb0, lv1, lv2, lv3)
    float iou1 = iou_box(p01.x, p01.y, p23.x, p23.y, lb0, l01.y, l23.x, l23.y);
    float iou2 = iou_box(p45.y, p67.x, p67.y, p89.x, lb0, l01.y, l23.x, l23.y);

    float b1 = 5.0f * (sq(p01.x - l01.x) + sq(p01.y - l01.y))
             + sq(sqrtf(p23.x) - sqrtf(l23.x)) + sq(sqrtf(p23.y) - sqrtf(l23.y))
             + sq(iou1 - p45.x)
             + 0.5f * p89.y * p89.y;

    float b2 = 5.0f * (sq(p45.y - l45.y) + sq(p67.x - l67.x))
             + sq(sqrtf(p67.y) - sqrtf(l67.y)) + sq(sqrtf(p89.x) - sqrtf(l89.x))
             + sq(iou2 - p89.y)
             + 0.5f * p45.x * p45.x;

    float obj_loss   = ((iou1 > iou2) ? b1 : b2) + cls;
    float noobj_loss = 0.5f * (p45.x * p45.x + p89.y * p89.y);
    float loss = (l45.x == 1.0f) ? obj_loss : noobj_loss;

    // ---- reduction: wave shuffle -> LDS -> one store per block ----
    #pragma unroll
    for (int off = 32; off > 0; off >>= 1)
        loss += __shfl_down(loss, off, 64);

    __shared__ float wsum[BLOCK / 64];
    const int lane = tid & 63;
    const int wv   = tid >> 6;
    if (lane == 0) wsum[wv] = loss;
    __syncthreads();
    if (tid == 0) {
        partials[blockIdx.x] = wsum[0] + wsum[1] + wsum[2] + wsum[3];
    }
}

__global__ __launch_bounds__(BLOCK) void yolo_reduce_kernel(
        const float* __restrict__ partials,
        float* __restrict__ out) {
    const int tid = threadIdx.x;
    float s = 0.0f;
    for (int i = tid; i < NBLK; i += BLOCK) s += partials[i];

    #pragma unroll
    for (int off = 32; off > 0; off >>= 1)
        s += __shfl_down(s, off, 64);

    __shared__ float wsum[BLOCK / 64];
    int lane = tid & 63;
    int wv   = tid >> 6;
    if (lane == 0) wsum[wv] = s;
    __syncthreads();
    if (tid == 0) {
        out[0] = (wsum[0] + wsum[1] + wsum[2] + wsum[3]) * (1.0f / (float)BATCH);
    }
}

extern "C" void kernel_launch(void* const* d_in, const int* in_sizes, int n_in,
                              void* d_out, int out_size, void* d_ws, size_t ws_size,
                              hipStream_t stream) {
    const float* preds  = (const float*)d_in[0];
    const float* labels = (const float*)d_in[1];
    float* out = (float*)d_out;
    float* partials = (float*)d_ws;   // NBLK floats = 12.25 KB

    yolo_partial_kernel<<<NBLK, BLOCK, 0, stream>>>(preds, labels, partials);
    yolo_reduce_kernel<<<1, BLOCK, 0, stream>>>(partials, out);
}